// Round 6
// baseline (364.835 us; speedup 1.0000x reference)
//
#include <hip/hip_runtime.h>
#include <hip/hip_bf16.h>

typedef short short8 __attribute__((ext_vector_type(8)));
typedef float f32x4 __attribute__((ext_vector_type(4)));

#define EW 12              // waves per k_edges block (768 threads) -> 2 blocks/CU, 24 waves/CU

// ---------- helpers ----------
static __device__ __forceinline__ float bf2f(unsigned int b) { return __uint_as_float(b << 16); }
static __device__ __forceinline__ short fb2s(float x) {       // f32 -> bf16 (RNE, for prepack)
    unsigned u = __float_as_uint(x);
    return (short)((u + 0x7FFFu + ((u >> 16) & 1u)) >> 16);
}
static __device__ __forceinline__ short fb2s_fast(float x) {  // f32 -> bf16 (round-half-up, 2 ops)
    return (short)((__float_as_uint(x) + 0x8000u) >> 16);
}
static __device__ __forceinline__ float silu(float x) {
    return x * __builtin_amdgcn_rcpf(1.0f + __expf(-x));
}
static __device__ __forceinline__ float load1(const void* p, long off, int isbf) {
    return isbf ? bf2f(((const unsigned short*)p)[off]) : ((const float*)p)[off];
}
static __device__ __forceinline__ void load4(const void* p, long off, int isbf, float* o) {
    if (isbf) {
        uint2 v = *(const uint2*)((const unsigned short*)p + off);
        o[0]=bf2f(v.x&0xffffu); o[1]=bf2f(v.x>>16);
        o[2]=bf2f(v.y&0xffffu); o[3]=bf2f(v.y>>16);
    } else {
        float4 v = *(const float4*)((const float*)p + off);
        o[0]=v.x; o[1]=v.y; o[2]=v.z; o[3]=v.w;
    }
}
// per-wave dtype detection (deterministic, wave-uniform; no barrier needed)
static __device__ __forceinline__ int detect_bf16(const void* nf) {
    const unsigned int* w = (const unsigned int*)nf;
    int lane = threadIdx.x & 63;
    unsigned int e = (w[lane] >> 7) & 0xFFu;
    unsigned long long m = __ballot(e >= 118u && e <= 132u);
    return __popcll(m) >= 32 ? 1 : 0;
}

// ---------- fused kernel: prepack (blocks 0..43) + acc zero + per-node projections ----------
#define NB 32
__global__ __launch_bounds__(256) void k_node(
    const void* __restrict__ nf, const void* __restrict__ W0, const void* __restrict__ W1,
    const void* __restrict__ w1, const void* __restrict__ w2,
    const void* __restrict__ w3, const void* __restrict__ w4,
    short* __restrict__ Bws, float* __restrict__ NA, float* __restrict__ acc, int n_nodes) {
    __shared__ float Nd0[NB * 68];
    __shared__ float Nd1[3 * NB * 68];
    __shared__ float W0L[8 * 68];
    __shared__ float W1L[8 * 68];
    const int tid = threadIdx.x;
    const int isbf = detect_bf16(nf);
    const long n0 = (long)blockIdx.x * NB;

    if (blockIdx.x < 44) {
        int idx = blockIdx.x * 256 + tid;
        int j = idx & 7, lane = (idx >> 3) & 63, tile = idx >> 9;
        int n16 = lane & 15, kq = lane >> 4;
        float v;
        if (tile < 4) {
            int k = kq * 8 + j, n = tile * 16 + n16;
            v = (k < 8) ? load1(w1, k * 64 + n, isbf) : 0.0f;
        } else if (tile < 12) {
            int t = (tile - 4) >> 1, kt = (tile - 4) & 1;
            int k = kt * 32 + kq * 8 + j, n = t * 16 + n16;
            v = load1(w2, k * 64 + n, isbf) * 0.125f;
        } else if (tile < 20) {
            int t = (tile - 12) >> 1, kt = (tile - 12) & 1;
            int k = kt * 32 + kq * 8 + j, n = t * 16 + n16;
            v = load1(w3, k * 64 + n, isbf) * 0.125f;
        } else {
            int kt = tile - 20;
            int k = kt * 32 + kq * 8 + j, n = n16;
            v = load1(w4, k * 16 + n, isbf) * 0.125f;
        }
        Bws[idx] = fb2s(v);
    }
    if (tid < NB) {
        long n = n0 + tid;
        if (n < n_nodes) acc[n] = 0.0f;
    }
    if (n0 >= n_nodes) return;

    for (int i = tid; i < 512; i += 256) {
        W0L[(i >> 6) * 68 + (i & 63)] = load1(W0, i, isbf);
        W1L[(i >> 6) * 68 + (i & 63)] = load1(W1, i, isbf);
    }
    if (isbf) {
        for (int i = tid; i < NB * 32; i += 256) {
            int node = i >> 5, c8 = (i & 31) * 8;
            long ng = n0 + node; if (ng > n_nodes - 1) ng = n_nodes - 1;
            uint4 v = *(const uint4*)((const unsigned short*)nf + ng * 256 + c8);
            float f[8];
            f[0]=bf2f(v.x&0xffffu); f[1]=bf2f(v.x>>16);
            f[2]=bf2f(v.y&0xffffu); f[3]=bf2f(v.y>>16);
            f[4]=bf2f(v.z&0xffffu); f[5]=bf2f(v.z>>16);
            f[6]=bf2f(v.w&0xffffu); f[7]=bf2f(v.w>>16);
            #pragma unroll
            for (int t = 0; t < 8; t++) {
                int col = c8 + t;
                if (col < 64) Nd0[node * 68 + col] = f[t];
                else {
                    int cc = col - 64, vv = cc / 3, kk = cc - vv * 3;
                    Nd1[(kk * NB + node) * 68 + vv] = f[t];
                }
            }
        }
    } else {
        for (int i = tid; i < NB * 64; i += 256) {
            int node = i >> 6, c4 = (i & 63) * 4;
            long ng = n0 + node; if (ng > n_nodes - 1) ng = n_nodes - 1;
            float4 v = *(const float4*)((const float*)nf + ng * 256 + c4);
            float f[4] = {v.x, v.y, v.z, v.w};
            #pragma unroll
            for (int t = 0; t < 4; t++) {
                int col = c4 + t;
                if (col < 64) Nd0[node * 68 + col] = f[t];
                else {
                    int cc = col - 64, vv = cc / 3, kk = cc - vv * 3;
                    Nd1[(kk * NB + node) * 68 + vv] = f[t];
                }
            }
        }
    }
    __syncthreads();

    const int wv = tid >> 6, lane = tid & 63;
    const int u = lane & 7, ln = lane >> 3;
    float sum[4] = {0.0f, 0.0f, 0.0f, 0.0f};

    if (wv == 0) {
        const float* w = &W0L[u * 68];
        for (int v0 = 0; v0 < 64; v0 += 4) {
            float4 w4 = *(const float4*)(w + v0);
            #pragma unroll
            for (int j = 0; j < 4; j++) {
                float4 nd = *(const float4*)&Nd0[(ln + 8 * j) * 68 + v0];
                sum[j] += w4.x * nd.x + w4.y * nd.y + w4.z * nd.z + w4.w * nd.w;
            }
        }
        #pragma unroll
        for (int j = 0; j < 4; j++) {
            long node = n0 + ln + 8 * j;
            if (node < n_nodes) NA[node * 32 + u] = sum[j] * 0.03125f;
        }
    } else {
        const int kk = wv - 1;
        const float* w = &W1L[u * 68];
        const float* nd1 = &Nd1[kk * NB * 68];
        for (int v0 = 0; v0 < 64; v0 += 4) {
            float4 w4 = *(const float4*)(w + v0);
            #pragma unroll
            for (int j = 0; j < 4; j++) {
                float4 nd = *(const float4*)&nd1[(ln + 8 * j) * 68 + v0];
                sum[j] += w4.x * nd.x + w4.y * nd.y + w4.z * nd.z + w4.w * nd.w;
            }
        }
        #pragma unroll
        for (int j = 0; j < 4; j++) {
            long node = n0 + ln + 8 * j;
            if (node < n_nodes) NA[node * 32 + 8 + u * 3 + kk] = sum[j] * 0.018042195912175804f;
        }
    }
}

// ---------- MFMA edge kernel: EW waves/block, 32 edges/wave ----------
// LDS = 22528 (W) + EW*4608 (H) = 77824 B -> 2 blocks/CU -> 24 waves/CU.
__global__ __launch_bounds__(EW * 64) void k_edges_mfma(
    const void* __restrict__ ef, const void* __restrict__ ea, const void* __restrict__ qc,
    const int* __restrict__ eidx, const void* __restrict__ nf,
    const short* __restrict__ Bws, const float* __restrict__ NA,
    float* __restrict__ acc, int n_edges) {
    __shared__ short W[11264];
    __shared__ short Hs[EW * 2304];
    const int tid = threadIdx.x, lane = tid & 63, wv = tid >> 6;
    const int n16 = lane & 15, kq = lane >> 4;
    const int isbf = detect_bf16(nf);

    {
        const uint4* src = (const uint4*)Bws;
        uint4* dst = (uint4*)W;
        for (int i = tid; i < 1408; i += EW * 64) dst[i] = src[i];
    }
    __syncthreads();

    const long E0 = (long)blockIdx.x * (EW * 32) + wv * 32;
    short* Hw = Hs + wv * 2304;

    int woff[4];
    #pragma unroll
    for (int t = 0; t < 4; t++)
        woff[t] = (((t * 2 + (n16 >> 3)) ^ (kq >> 1)) << 3) + (n16 & 7);
    const int rbit = (n16 >> 3) & 1;

    short8 a1[2];
    #pragma unroll
    for (int mt = 0; mt < 2; mt++) {
        short8 a = {0,0,0,0,0,0,0,0};
        if (kq == 0) {
            long e = E0 + mt * 16 + n16;
            if (e > n_edges - 1) e = n_edges - 1;
            if (isbf) {
                a = *(const short8*)((const unsigned short*)ef + e * 8);
            } else {
                const float* pe = (const float*)ef + e * 8;
                float4 v0 = *(const float4*)pe, v1 = *(const float4*)(pe + 4);
                a[0]=fb2s(v0.x); a[1]=fb2s(v0.y); a[2]=fb2s(v0.z); a[3]=fb2s(v0.w);
                a[4]=fb2s(v1.x); a[5]=fb2s(v1.y); a[6]=fb2s(v1.z); a[7]=fb2s(v1.w);
            }
        }
        a1[mt] = a;
    }

    const f32x4 zero = {0.0f, 0.0f, 0.0f, 0.0f};

    {   // layer 1: [32x8pad32] @ [8x64]
        f32x4 c1[2][4];
        #pragma unroll
        for (int t = 0; t < 4; t++) {
            short8 b = *(const short8*)(W + t * 512 + lane * 8);
            #pragma unroll
            for (int mt = 0; mt < 2; mt++)
                c1[mt][t] = __builtin_amdgcn_mfma_f32_16x16x32_bf16(a1[mt], b, zero, 0, 0, 0);
        }
        #pragma unroll
        for (int mt = 0; mt < 2; mt++)
            #pragma unroll
            for (int t = 0; t < 4; t++)
                #pragma unroll
                for (int r = 0; r < 4; r++) {
                    float v = silu(c1[mt][t][r] * 0.35355339059327373f);
                    Hw[(mt * 16 + kq * 4 + r) * 72 + woff[t]] = fb2s_fast(v);
                }
    }

    #pragma unroll
    for (int L = 0; L < 2; L++) {   // layers 2,3: [32x64] @ [64x64]
        const int base = (L == 0) ? 4 : 12;
        short8 a[2][2];
        #pragma unroll
        for (int mt = 0; mt < 2; mt++)
            #pragma unroll
            for (int kt = 0; kt < 2; kt++)
                a[mt][kt] = *(const short8*)(Hw + (mt * 16 + n16) * 72 + (((kt * 4 + kq) ^ rbit) << 3));
        f32x4 c2[2][4];
        #pragma unroll
        for (int mt = 0; mt < 2; mt++)
            #pragma unroll
            for (int t = 0; t < 4; t++) c2[mt][t] = zero;
        #pragma unroll
        for (int kt = 0; kt < 2; kt++)
            #pragma unroll
            for (int t = 0; t < 4; t++) {
                short8 b = *(const short8*)(W + (base + t * 2 + kt) * 512 + lane * 8);
                #pragma unroll
                for (int mt = 0; mt < 2; mt++)
                    c2[mt][t] = __builtin_amdgcn_mfma_f32_16x16x32_bf16(a[mt][kt], b, c2[mt][t], 0, 0, 0);
            }
        #pragma unroll
        for (int mt = 0; mt < 2; mt++)
            #pragma unroll
            for (int t = 0; t < 4; t++)
                #pragma unroll
                for (int r = 0; r < 4; r++) {
                    float v = silu(c2[mt][t][r]);
                    Hw[(mt * 16 + kq * 4 + r) * 72 + woff[t]] = fb2s_fast(v);
                }
    }

    float* TP = (float*)Hw;   // layer 4 output: 32 rows x stride 20 f32
    {
        short8 a[2][2];
        #pragma unroll
        for (int mt = 0; mt < 2; mt++)
            #pragma unroll
            for (int kt = 0; kt < 2; kt++)
                a[mt][kt] = *(const short8*)(Hw + (mt * 16 + n16) * 72 + (((kt * 4 + kq) ^ rbit) << 3));
        f32x4 c4[2] = {zero, zero};
        #pragma unroll
        for (int kt = 0; kt < 2; kt++) {
            short8 b = *(const short8*)(W + (20 + kt) * 512 + lane * 8);
            #pragma unroll
            for (int mt = 0; mt < 2; mt++)
                c4[mt] = __builtin_amdgcn_mfma_f32_16x16x32_bf16(a[mt][kt], b, c4[mt], 0, 0, 0);
        }
        #pragma unroll
        for (int mt = 0; mt < 2; mt++)
            #pragma unroll
            for (int r = 0; r < 4; r++)
                TP[(mt * 16 + kq * 4 + r) * 20 + n16] = c4[mt][r];
    }

    {   // epilogue: 2 lanes per edge
        const int el = lane >> 1, h = lane & 1;
        const long e = E0 + el;
        long ec = e;
        if (ec > n_edges - 1) ec = n_edges - 1;
        const int s = eidx[ec];
        const int r = eidx[(long)n_edges + ec];

        float4 t0 = *(const float4*)(TP + el * 20 + h * 4);
        float4 t1 = *(const float4*)(TP + el * 20 + 8 + h * 4);
        float tp0[4] = {t0.x, t0.y, t0.z, t0.w};
        float tp1[4] = {t1.x, t1.y, t1.z, t1.w};

        float q[4];
        load4(qc, (long)s * 8 + h * 4, isbf, q);
        float eav[4];
        load4(ea, ec * 4, isbf, eav);

        const float* nr = NA + (long)r * 32;
        float4 n0 = *(const float4*)(nr + h * 4);
        float t12[12];
        *(float4*)(t12 + 0) = *(const float4*)(nr + 8 + h * 12);
        *(float4*)(t12 + 4) = *(const float4*)(nr + 12 + h * 12);
        *(float4*)(t12 + 8) = *(const float4*)(nr + 16 + h * 12);

        float n0a[4] = {n0.x, n0.y, n0.z, n0.w};
        float p = 0.0f;
        #pragma unroll
        for (int i = 0; i < 4; i++) {
            float d = eav[1] * t12[i * 3] + eav[2] * t12[i * 3 + 1] + eav[3] * t12[i * 3 + 2];
            p += tp0[i] * q[i] * eav[0] * n0a[i] + tp1[i] * q[i] * d;
        }
        p += __shfl_xor(p, 1);
        if (h == 0 && e < n_edges) atomicAdd(&acc[r], p);
    }
}

// ---------- accumulator -> output ----------
__global__ void k_out(const float* __restrict__ acc, void* __restrict__ out,
                      const void* __restrict__ nf, int n) {
    const int isbf = detect_bf16(nf);
    int i = blockIdx.x * 256 + threadIdx.x;
    if (i >= n) return;
    if (isbf) ((__hip_bfloat16*)out)[i] = __float2bfloat16(acc[i]);
    else      ((float*)out)[i] = acc[i];
}

// ---------- launch ----------
extern "C" void kernel_launch(void* const* d_in, const int* in_sizes, int n_in,
                              void* d_out, int out_size, void* d_ws, size_t ws_size,
                              hipStream_t stream) {
    const void* node_feats      = d_in[0];
    const void* charges_induced = d_in[2];
    const void* edge_feats      = d_in[3];
    const void* edge_attrs      = d_in[4];
    const void* mlp_w1          = d_in[6];
    const void* mlp_w2          = d_in[7];
    const void* mlp_w3          = d_in[8];
    const void* mlp_w4          = d_in[9];
    const void* W0              = d_in[10];
    const void* W1              = d_in[11];
    const int*  edge_index      = (const int*)d_in[12];

    const int n_nodes = in_sizes[0] / 256;
    const int n_edges = in_sizes[3] / 8;

    short* Bws = (short*)d_ws;                                 // 11264 shorts
    float* NA  = (float*)((char*)d_ws + 22528);                // n_nodes*32 f32
    float* acc = NA + (size_t)n_nodes * 32;                    // n_nodes f32

    int nblk = (n_nodes + NB - 1) / NB;
    if (nblk < 44) nblk = 44;
    k_node<<<nblk, 256, 0, stream>>>(node_feats, W0, W1,
        mlp_w1, mlp_w2, mlp_w3, mlp_w4, Bws, NA, acc, n_nodes);
    const int epb = EW * 32;   // edges per block
    k_edges_mfma<<<(n_edges + epb - 1) / epb, EW * 64, 0, stream>>>(
        edge_feats, edge_attrs, charges_induced, edge_index, node_feats, Bws, NA, acc, n_edges);
    k_out<<<(n_nodes + 255) / 256, 256, 0, stream>>>(acc, d_out, node_feats, n_nodes);
}